// Round 7
// baseline (237.818 us; speedup 1.0000x reference)
//
#include <hip/hip_runtime.h>
#include <math.h>

#define BB 2
#define CC 192
#define DI 384
#define SS 16
#define RR 12
#define KK 4
#define NB 256
#define NT 512

// ---------------- global barrier (all NB blocks co-resident) ----------------
__device__ __forceinline__ void gsync(unsigned int* bar, unsigned int target) {
  __syncthreads();
  if (threadIdx.x == 0) {
    __threadfence();   // release: writeback this XCD's L2 so other XCDs see our writes
    __hip_atomic_fetch_add(bar, 1u, __ATOMIC_ACQ_REL, __HIP_MEMORY_SCOPE_AGENT);
    while (__hip_atomic_load(bar, __ATOMIC_ACQUIRE, __HIP_MEMORY_SCOPE_AGENT) < target)
      __builtin_amdgcn_s_sleep(2);
    __threadfence();   // acquire side: invalidate stale cache before phase reads
  }
  __syncthreads();
}

// ---------------- K1: one pass over x, all three axis-mean reductions (unchanged) ----------------
__global__ void k_reduce(const float* __restrict__ x, float* __restrict__ seq) {
  int bc = blockIdx.x; int b = bc / CC, c = bc % CC;
  const float* base = x + (size_t)bc * 32768;
  int t = threadIdx.x;
  int w = t & 31, r = t >> 5;
  float acc = 0.f;
  __shared__ float sH[32];
  __shared__ float sMat[1024];
  if (t < 32) sH[t] = 0.f;
  __syncthreads();
  for (int h = 0; h < 32; ++h) {
    float v = base[r * 1024 + h * 32 + w];
    acc += v;
    float vv = v;
    #pragma unroll
    for (int off = 32; off > 0; off >>= 1) vv += __shfl_down(vv, off, 64);
    if ((t & 63) == 0) atomicAdd(&sH[h], vv);
  }
  sMat[t] = acc;
  float s0 = acc;
  #pragma unroll
  for (int off = 16; off > 0; off >>= 1) s0 += __shfl_down(s0, off, 32);
  if (w == 0) seq[((0 * BB + b) * 32 + r) * CC + c] = s0 * (1.f / 1024.f);
  __syncthreads();
  if (t < 32) {
    float s2 = 0.f;
    for (int rr = 0; rr < 32; ++rr) s2 += sMat[rr * 32 + t];
    seq[((2 * BB + b) * 32 + t) * CC + c] = s2 * (1.f / 1024.f);
    seq[((1 * BB + b) * 32 + t) * CC + c] = sH[t] * (1.f / 1024.f);
  }
}

// ---------------- K2: persistent middle megakernel: LN+inproj | conv+xp+dt | scan | mz | gate ----------------
__global__ __launch_bounds__(NT, 2) void k_mid(
    const float* __restrict__ seq, const float* __restrict__ ln_w,
    const float* __restrict__ ln_b, const float* __restrict__ in_w,
    const float* __restrict__ conv_w, const float* __restrict__ conv_b,
    const float* __restrict__ xp_w, const float* __restrict__ dt_w,
    const float* __restrict__ dt_b, const float* __restrict__ A_log,
    const float* __restrict__ Dskip, const float* __restrict__ out_w,
    const float* __restrict__ up_w, const float* __restrict__ up_b,
    const float* __restrict__ Wg_w, const float* __restrict__ Wg_b,
    const float* __restrict__ Ws_w, const float* __restrict__ Ws_b,
    const float* __restrict__ Wm_w, const float* __restrict__ Wm_b,
    const float* __restrict__ po_w,
    float* __restrict__ xmz, float* __restrict__ xc, float* __restrict__ dbc,
    float* __restrict__ dtb, float* __restrict__ y, float* __restrict__ ymean,
    float* __restrict__ zrow, float* __restrict__ P, unsigned int* bar) {
  __shared__ float lds[7680];
  int bid = blockIdx.x, t = threadIdx.x;

  // ======== phase 1: LN + in-proj (192 token jobs) ========
  if (bid < 192) {
    int tok = bid, i = tok >> 6;
    float* srow = lds;           // 192
    float* sred = lds + 192;     // 8
    float v = (t < CC) ? seq[tok * CC + t] : 0.f;
    float s = v, q = v * v;
    #pragma unroll
    for (int off = 32; off > 0; off >>= 1) { s += __shfl_down(s, off, 64); q += __shfl_down(q, off, 64); }
    if (t < 256 && (t & 63) == 0) { sred[t >> 6] = s; sred[4 + (t >> 6)] = q; }
    __syncthreads();
    float S = sred[0] + sred[1] + sred[2] + sred[3];
    float Q = sred[4] + sred[5] + sred[6] + sred[7];
    float mu = S / CC;
    float ri = rsqrtf(Q / CC - mu * mu + 1e-5f);
    if (t < CC) srow[t] = (v - mu) * ri * ln_w[i * CC + t] + ln_b[i * CC + t];
    __syncthreads();
    const float4* sr = (const float4*)srow;
    for (int j = t; j < 768; j += NT) {
      const float4* wr = (const float4*)(in_w + ((size_t)i * 768 + j) * CC);
      float acc = 0.f;
      #pragma unroll 8
      for (int c4 = 0; c4 < CC / 4; ++c4) {
        float4 a = wr[c4], bq = sr[c4];
        acc += a.x * bq.x + a.y * bq.y + a.z * bq.z + a.w * bq.w;
      }
      xmz[(size_t)tok * 768 + j] = acc;
    }
  }
  gsync(bar, NB);

  // ======== phase 2: conv+silu + xp-proj + dt-proj+softplus (192 token jobs) ========
  if (bid < 192) {
    int tok = bid; int l = tok & 31; int tb = tok >> 5; int i = tb / BB;
    float* xcl  = lds;          // 384
    float* dbcl = lds + 384;    // 44
    if (t < 384) {
      int di = t;
      const float* cw = conv_w + ((size_t)i * DI + di) * KK;
      float acc = conv_b[i * DI + di];
      #pragma unroll
      for (int k = 0; k < KK; ++k) {
        int ls = l + k - 3;
        if (ls >= 0) acc += cw[k] * xmz[(size_t)(tb * 32 + ls) * 768 + di];
      }
      acc = acc / (1.f + expf(-acc));
      xcl[di] = acc;
      xc[(size_t)tok * DI + di] = acc;
    }
    __syncthreads();
    if (t < 352) {
      int o = t >> 3, ln8 = t & 7;
      const float4* wr = (const float4*)(xp_w + ((size_t)i * 44 + o) * DI);
      const float4* xv = (const float4*)xcl;
      float acc = 0.f;
      #pragma unroll
      for (int c4 = ln8 * 12; c4 < ln8 * 12 + 12; ++c4) {
        float4 a = wr[c4], bq = xv[c4];
        acc += a.x * bq.x + a.y * bq.y + a.z * bq.z + a.w * bq.w;
      }
      #pragma unroll
      for (int off = 4; off > 0; off >>= 1) acc += __shfl_xor(acc, off, 8);
      if (ln8 == 0) { dbcl[o] = acc; dbc[tok * 44 + o] = acc; }
    }
    __syncthreads();
    if (t < 384) {
      int di = t;
      const float* wr = dt_w + ((size_t)i * DI + di) * RR;
      float acc = dt_b[i * DI + di];
      #pragma unroll
      for (int r = 0; r < RR; ++r) acc += wr[r] * dbcl[r];
      float sp = (acc > 20.f) ? acc : log1pf(expf(acc));
      dtb[(size_t)tok * DI + di] = sp;
    }
  }
  gsync(bar, 2 * NB);

  // ======== phase 3: scan (144 jobs: 6 ib x 9... 24 chunks of 16 di) ========
  if (bid < 144) {
    int ib = bid / 24;
    int di0 = (bid % 24) * 16;
    int i = ib / BB;
    float* sdt  = lds;           // [32][16]
    float* sxc  = lds + 512;
    float* sz   = lds + 1024;
    float* sB   = lds + 1536;    // [32][16]
    float* sC   = lds + 2048;
    float* spp  = lds + 2560;    // [16][16*17]
    float* sy   = lds + 6912;    // [32][16]
    float* sDsk = lds + 7424;    // 16
    {
      int l = t >> 4, gg = t & 15;
      int tok = ib * 32 + l;
      sdt[t] = dtb[(size_t)tok * DI + di0 + gg];
      sxc[t] = xc[(size_t)tok * DI + di0 + gg];
      sz[t]  = xmz[(size_t)tok * 768 + DI + di0 + gg];
      sB[t] = dbc[tok * 44 + RR + gg];
      sC[t] = dbc[tok * 44 + RR + SS + gg];
      if (t < 16) sDsk[t] = Dskip[i * DI + di0 + t];
    }
    int g = t >> 4, s = t & 15;   // for t<256
    float A = 0.f;
    if (t < 256) A = -expf(A_log[((size_t)i * DI + di0 + g) * SS + s]);
    float h = 0.f;
    __syncthreads();
    #pragma unroll
    for (int half = 0; half < 2; ++half) {
      if (t < 256) {
        #pragma unroll
        for (int l0 = 0; l0 < 16; ++l0) {
          int l = half * 16 + l0;
          float dtt = sdt[l * 16 + g];
          h = expf(dtt * A) * h + dtt * sxc[l * 16 + g] * sB[l * 16 + s];
          spp[l0 * 272 + g * 17 + s] = h * sC[l * 16 + s];
        }
      }
      __syncthreads();
      if (t < 256) {
        int l0 = t >> 4, g2 = t & 15;
        int l = half * 16 + l0;
        float sum = 0.f;
        #pragma unroll
        for (int s2 = 0; s2 < 16; ++s2) sum += spp[l0 * 272 + g2 * 17 + s2];
        float xt = sxc[l * 16 + g2];
        float z  = sz[l * 16 + g2];
        float yv = (sum + sDsk[g2] * xt) * (z / (1.f + expf(-z)));
        y[(size_t)(ib * 32 + l) * DI + di0 + g2] = yv;
        sy[l * 16 + g2] = yv;
      }
      __syncthreads();
    }
    if (t < 16) {
      float sum = 0.f;
      #pragma unroll
      for (int l = 0; l < 32; ++l) sum += sy[l * 16 + t];
      ymean[ib * DI + di0 + t] = sum * (1.f / 32.f);
    }
  }
  gsync(bar, 3 * NB);

  // ======== phase 4: mz = up_b + up_w @ (out_w @ {y[tok] | ymean}) (198 jobs) ========
  if (bid < 198) {
    int j = bid;
    float* src   = lds;          // 384
    float* pa    = lds + 384;    // 384
    float* mrowL = lds + 768;    // 192
    int i = (j < 192) ? (j >> 6) : (j - 192) / BB;
    if (t < 384) src[t] = (j < 192) ? y[(size_t)j * DI + t] : ymean[(j - 192) * DI + t];
    __syncthreads();
    if (t < 384) {
      int o = t >> 1, half = t & 1;
      const float4* wr = (const float4*)(out_w + ((size_t)i * CC + o) * DI);
      const float4* sv = (const float4*)src;
      float acc = 0.f;
      #pragma unroll 8
      for (int c4 = half * 48; c4 < half * 48 + 48; ++c4) {
        float4 a = wr[c4], bq = sv[c4];
        acc += a.x * bq.x + a.y * bq.y + a.z * bq.z + a.w * bq.w;
      }
      pa[t] = acc;
    }
    __syncthreads();
    if (t < 192) mrowL[t] = pa[2 * t] + pa[2 * t + 1];
    __syncthreads();
    if (t < 384) {
      int o = t >> 1, half = t & 1;
      const float4* ur = (const float4*)(up_w + ((size_t)i * CC + o) * CC);
      const float4* mv = (const float4*)mrowL;
      float acc = 0.f;
      #pragma unroll 8
      for (int c4 = half * 24; c4 < half * 24 + 24; ++c4) {
        float4 a = ur[c4], bq = mv[c4];
        acc += a.x * bq.x + a.y * bq.y + a.z * bq.z + a.w * bq.w;
      }
      pa[t] = acc;
    }
    __syncthreads();
    if (t < 192) zrow[(size_t)j * CC + t] = up_b[i * CC + t] + pa[2 * t] + pa[2 * t + 1];
  }
  gsync(bar, 4 * NB);

  // ======== phase 5: gate (192 token jobs) ========
  if (bid < 192) {
    int blk = bid; int gb = blk >> 5; int g = gb / BB, b = gb - g * BB;
    int o1 = (g == 0) ? 1 : 0, o2 = (g == 2) ? 1 : 2;
    float* zr   = lds;           // 192
    float* zm0  = lds + 192;
    float* zm1  = lds + 384;
    float* arow = lds + 576;
    float* ygr  = lds + 768;
    float* pa   = lds + 960;     // 384
    float* pb   = lds + 1344;    // 384
    if (t < CC) {
      zr[t]  = zrow[(size_t)blk * CC + t];
      zm0[t] = zrow[(size_t)(192 + o1 * BB + b) * CC + t];
    } else if (t < 2 * CC) {
      int tt = t - CC;
      zm1[tt] = zrow[(size_t)(192 + o2 * BB + b) * CC + tt];
    }
    __syncthreads();
    int o = (t < 192) ? t : t - 192;
    int ph = (t < 192) ? 0 : 1;
    if (t < 384) {
      const float4* wr = (const float4*)(Ws_w + (size_t)o * CC);
      const float4* zv = (const float4*)zr;
      float acc = 0.f;
      #pragma unroll 4
      for (int c4 = ph * 24; c4 < ph * 24 + 24; ++c4) {
        float4 a = wr[c4], bq = zv[c4];
        acc += a.x * bq.x + a.y * bq.y + a.z * bq.z + a.w * bq.w;
      }
      pa[t] = acc;
      const float4* gwr = (const float4*)(Wg_w + (size_t)o * 2 * CC + ph * CC);
      const float4* gmv = (const float4*)(ph == 0 ? zm0 : zm1);
      float acc2 = 0.f;
      #pragma unroll 4
      for (int c4 = 0; c4 < 48; ++c4) {
        float4 a = gwr[c4], bq = gmv[c4];
        acc2 += a.x * bq.x + a.y * bq.y + a.z * bq.z + a.w * bq.w;
      }
      pb[t] = acc2;
    }
    __syncthreads();
    if (t < 192) {
      float a = (Ws_b[t] + pa[t] + pa[t + 192]) + (Wg_b[t] + pb[t] + pb[t + 192]);
      arow[t] = a > 0.f ? a : 0.f;
    }
    __syncthreads();
    if (t < 384) {
      const float4* mr = (const float4*)(Wm_w + (size_t)o * CC);
      const float4* av = (const float4*)arow;
      float acc = 0.f;
      #pragma unroll 4
      for (int c4 = ph * 24; c4 < ph * 24 + 24; ++c4) {
        float4 a = mr[c4], bq = av[c4];
        acc += a.x * bq.x + a.y * bq.y + a.z * bq.z + a.w * bq.w;
      }
      pa[t] = acc;
    }
    __syncthreads();
    if (t < 192) {
      float am = Wm_b[t] + pa[t] + pa[t + 192];
      am = 1.f / (1.f + expf(-am));
      ygr[t] = am * zr[t];
    }
    __syncthreads();
    if (t < 384) {
      const float4* pr = (const float4*)(po_w + (size_t)o * (3 * CC) + g * CC);
      const float4* yv = (const float4*)ygr;
      float acc = 0.f;
      #pragma unroll 4
      for (int c4 = ph * 24; c4 < ph * 24 + 24; ++c4) {
        float4 a = pr[c4], bq = yv[c4];
        acc += a.x * bq.x + a.y * bq.y + a.z * bq.z + a.w * bq.w;
      }
      pb[t] = acc;
    }
    __syncthreads();
    if (t < 192) P[(size_t)blk * CC + t] = pb[t] + pb[t + 192];
  }
}

// ---------------- K3: final: warp-parallel separable stats + broadcast + residual (unchanged) ----------------
__global__ void k_final(const float* __restrict__ x, const float* __restrict__ P,
                        const float* __restrict__ po_b, const float* __restrict__ rs_p,
                        float* __restrict__ out) {
  int bc = blockIdx.x >> 1; int half = blockIdx.x & 1;
  int b = bc / CC, c = bc % CC;
  __shared__ float p0[32], p1[32], p2[32];
  __shared__ float sbase;
  int t = threadIdx.x;
  if (t < 32) {
    float v0 = P[((0 * BB + b) * 32 + t) * CC + c];
    float v1 = P[((1 * BB + b) * 32 + t) * CC + c];
    float v2 = P[((2 * BB + b) * 32 + t) * CC + c];
    float s0 = v0, q0 = v0 * v0, s1 = v1, q1 = v1 * v1, s2 = v2, q2 = v2 * v2;
    #pragma unroll
    for (int off = 16; off > 0; off >>= 1) {
      s0 += __shfl_xor(s0, off, 32); q0 += __shfl_xor(q0, off, 32);
      s1 += __shfl_xor(s1, off, 32); q1 += __shfl_xor(q1, off, 32);
      s2 += __shfl_xor(s2, off, 32); q2 += __shfl_xor(q2, off, 32);
    }
    float m0 = s0 * (1.f / 32.f), m1 = s1 * (1.f / 32.f), m2 = s2 * (1.f / 32.f);
    float var = (q0 * (1.f / 32.f) - m0 * m0) + (q1 * (1.f / 32.f) - m1 * m1) + (q2 * (1.f / 32.f) - m2 * m2);
    float mu = po_b[c] + m0 + m1 + m2;
    float sc = rs_p[0] * rsqrtf(var + 1e-5f);
    p0[t] = v0 * sc; p1[t] = v1 * sc; p2[t] = v2 * sc;
    if (t == 0) sbase = sc * (po_b[c] - mu);
  }
  __syncthreads();
  float basev = sbase;
  const float4* xin = (const float4*)(x + (size_t)bc * 32768);
  float4* xo = (float4*)(out + (size_t)bc * 32768);
  int q0i = half * 4096;
  #pragma unroll 4
  for (int q = q0i + t; q < q0i + 4096; q += 256) {
    int d = q >> 8, h = (q >> 3) & 31, w4 = (q & 7) * 4;
    float add = basev + p0[d] + p1[h];
    float4 v = xin[q];
    v.x += add + p2[w4];
    v.y += add + p2[w4 + 1];
    v.z += add + p2[w4 + 2];
    v.w += add + p2[w4 + 3];
    xo[q] = v;
  }
}

extern "C" void kernel_launch(void* const* d_in, const int* in_sizes, int n_in,
                              void* d_out, int out_size, void* d_ws, size_t ws_size,
                              hipStream_t stream) {
  const float* x      = (const float*)d_in[0];
  const float* ln_w   = (const float*)d_in[1];
  const float* ln_b   = (const float*)d_in[2];
  const float* in_w   = (const float*)d_in[3];
  const float* conv_w = (const float*)d_in[4];
  const float* conv_b = (const float*)d_in[5];
  const float* xp_w   = (const float*)d_in[6];
  const float* dt_w   = (const float*)d_in[7];
  const float* dt_b   = (const float*)d_in[8];
  const float* A_log  = (const float*)d_in[9];
  const float* Dskip  = (const float*)d_in[10];
  const float* out_w  = (const float*)d_in[11];
  const float* up_w   = (const float*)d_in[12];
  const float* up_b   = (const float*)d_in[13];
  const float* Wg_w   = (const float*)d_in[14];
  const float* Wg_b   = (const float*)d_in[15];
  const float* Ws_w   = (const float*)d_in[16];
  const float* Ws_b   = (const float*)d_in[17];
  const float* Wm_w   = (const float*)d_in[18];
  const float* Wm_b   = (const float*)d_in[19];
  const float* po_w   = (const float*)d_in[20];
  const float* po_b   = (const float*)d_in[21];
  const float* rs_p   = (const float*)d_in[22];
  float* out = (float*)d_out;

  float* ws    = (float*)d_ws;
  float* seq   = ws;                 // 36864
  float* xmz   = seq   + 36864;      // 147456
  float* xc    = xmz   + 147456;     // 73728
  float* dbc   = xc    + 73728;      // 8448
  float* dtb   = dbc   + 8448;       // 73728
  float* y     = dtb   + 73728;      // 73728
  float* ymean = y     + 73728;      // 2304
  float* zrow  = ymean + 2304;       // 38016
  float* P     = zrow  + 38016;      // 36864
  unsigned int* bar = (unsigned int*)(P + 36864);

  hipMemsetAsync((void*)bar, 0, 64, stream);
  k_reduce<<<dim3(BB * CC),     dim3(1024), 0, stream>>>(x, seq);
  k_mid   <<<dim3(NB),          dim3(NT),   0, stream>>>(seq, ln_w, ln_b, in_w, conv_w, conv_b,
                                                         xp_w, dt_w, dt_b, A_log, Dskip, out_w,
                                                         up_w, up_b, Wg_w, Wg_b, Ws_w, Ws_b,
                                                         Wm_w, Wm_b, po_w,
                                                         xmz, xc, dbc, dtb, y, ymean, zrow, P, bar);
  k_final <<<dim3(BB * CC * 2), dim3(256),  0, stream>>>(x, P, po_b, rs_p, out);
}

// Round 8
// 112.299 us; speedup vs baseline: 2.1177x; 2.1177x over previous
//
#include <hip/hip_runtime.h>
#include <math.h>

#define BB 2
#define CC 192
#define DI 384
#define SS 16
#define RR 12
#define KK 4

// ---------------- K1: one pass over x, all three axis-mean reductions ----------------
// grid = B*C, block = 1024. seq layout: seq[i][b][pos][c]
__global__ void k_reduce(const float* __restrict__ x, float* __restrict__ seq) {
  int bc = blockIdx.x; int b = bc / CC, c = bc % CC;
  const float* base = x + (size_t)bc * 32768;
  int t = threadIdx.x;
  int w = t & 31, r = t >> 5;
  float acc = 0.f;
  __shared__ float sH[32];
  __shared__ float sMat[1024];
  if (t < 32) sH[t] = 0.f;
  __syncthreads();
  for (int h = 0; h < 32; ++h) {
    float v = base[r * 1024 + h * 32 + w];
    acc += v;
    float vv = v;
    #pragma unroll
    for (int off = 32; off > 0; off >>= 1) vv += __shfl_down(vv, off, 64);
    if ((t & 63) == 0) atomicAdd(&sH[h], vv);
  }
  sMat[t] = acc;
  float s0 = acc;
  #pragma unroll
  for (int off = 16; off > 0; off >>= 1) s0 += __shfl_down(s0, off, 32);
  if (w == 0) seq[((0 * BB + b) * 32 + r) * CC + c] = s0 * (1.f / 1024.f);
  __syncthreads();
  if (t < 32) {
    float s2 = 0.f;
    for (int rr = 0; rr < 32; ++rr) s2 += sMat[rr * 32 + t];
    seq[((2 * BB + b) * 32 + t) * CC + c] = s2 * (1.f / 1024.f);
    seq[((1 * BB + b) * 32 + t) * CC + c] = sH[t] * (1.f / 1024.f);
  }
}

// ---------------- K2: LN (recomputed per block) + in-proj, wide ----------------
// grid = 576 (192 tok x 3 chunks), block = 256
__global__ void k_lninproj(const float* __restrict__ seq, const float* __restrict__ ln_w,
                           const float* __restrict__ ln_b, const float* __restrict__ in_w,
                           float* __restrict__ xmz) {
  int blk = blockIdx.x;
  int tok = blk / 3, chunk = blk - tok * 3;
  int i = tok >> 6;
  int t = threadIdx.x;
  __shared__ float srow[CC];
  __shared__ float sw[4], qw[4];
  float v = (t < CC) ? seq[tok * CC + t] : 0.f;
  float s = v, q = v * v;
  #pragma unroll
  for (int off = 32; off > 0; off >>= 1) { s += __shfl_down(s, off, 64); q += __shfl_down(q, off, 64); }
  if ((t & 63) == 0) { sw[t >> 6] = s; qw[t >> 6] = q; }
  __syncthreads();
  float S = sw[0] + sw[1] + sw[2] + sw[3];
  float Q = qw[0] + qw[1] + qw[2] + qw[3];
  float mu = S / CC;
  float var = Q / CC - mu * mu;
  if (t < CC) srow[t] = (v - mu) * rsqrtf(var + 1e-5f) * ln_w[i * CC + t] + ln_b[i * CC + t];
  __syncthreads();
  int j = chunk * 256 + t;   // 0..767
  const float4* wr = (const float4*)(in_w + ((size_t)i * 768 + j) * CC);
  const float4* sr = (const float4*)srow;
  float acc = 0.f;
  #pragma unroll 8
  for (int c4 = 0; c4 < CC / 4; ++c4) {
    float4 a = wr[c4], bq = sr[c4];
    acc += a.x * bq.x + a.y * bq.y + a.z * bq.z + a.w * bq.w;
  }
  xmz[(size_t)tok * 768 + j] = acc;
}

// ---------------- K3: conv+silu + xp-proj, per token ----------------
// grid = 192, block = 384
__global__ void k_convxp(const float* __restrict__ xmz, const float* __restrict__ conv_w,
                         const float* __restrict__ conv_b, const float* __restrict__ xp_w,
                         float* __restrict__ xc, float* __restrict__ dbc) {
  int tok = blockIdx.x; int l = tok & 31; int tb = tok >> 5; int i = tb / BB;
  int t = threadIdx.x;
  __shared__ float xcl[DI];
  {
    int di = t;
    const float* cw = conv_w + ((size_t)i * DI + di) * KK;
    float acc = conv_b[i * DI + di];
    #pragma unroll
    for (int k = 0; k < KK; ++k) {
      int ls = l + k - 3;
      if (ls >= 0) acc += cw[k] * xmz[(size_t)(tb * 32 + ls) * 768 + di];
    }
    acc = acc / (1.f + expf(-acc));
    xcl[di] = acc;
    xc[(size_t)tok * DI + di] = acc;
  }
  __syncthreads();
  if (t < 352) {
    int o = t >> 3, ln8 = t & 7;
    const float4* wr = (const float4*)(xp_w + ((size_t)i * 44 + o) * DI);
    const float4* xv = (const float4*)xcl;
    float acc = 0.f;
    #pragma unroll
    for (int c4 = ln8 * 12; c4 < ln8 * 12 + 12; ++c4) {
      float4 a = wr[c4], bq = xv[c4];
      acc += a.x * bq.x + a.y * bq.y + a.z * bq.z + a.w * bq.w;
    }
    #pragma unroll
    for (int off = 4; off > 0; off >>= 1) acc += __shfl_xor(acc, off, 8);
    if (ln8 == 0) dbc[tok * 44 + o] = acc;
  }
}

// ---------------- K4: scan (dt-proj+softplus inlined at staging) ----------------
// grid = 288 (6 ib x 48 chunks), block = 128 (8 di x 16 s)
__global__ void k_scan(const float* __restrict__ dbc, const float* __restrict__ xc,
                       const float* __restrict__ xmz, const float* __restrict__ dt_w,
                       const float* __restrict__ dt_b, const float* __restrict__ A_log,
                       const float* __restrict__ Dskip, float* __restrict__ y,
                       float* __restrict__ ymean) {
  int ib = blockIdx.x / 48;
  int di0 = (blockIdx.x % 48) * 8;
  int i = ib / BB;
  int t = threadIdx.x;
  int g = t >> 4, s = t & 15;
  int di = di0 + g;
  __shared__ float sdt[32][8], sxc[32][8], sz[32][8];
  __shared__ float sB[32][SS], sC[32][SS];
  __shared__ float spp[32 * 136];
  __shared__ float sy[32][8];
  __shared__ float sDsk[8];
  #pragma unroll
  for (int j = t; j < 256; j += 128) {
    int l = j >> 3, gg = j & 7;
    int tok = ib * 32 + l;
    sxc[l][gg] = xc[(size_t)tok * DI + di0 + gg];
    sz[l][gg]  = xmz[(size_t)tok * 768 + DI + di0 + gg];
    // dt-proj + softplus inlined
    const float* wr = dt_w + ((size_t)i * DI + di0 + gg) * RR;
    float acc = dt_b[i * DI + di0 + gg];
    #pragma unroll
    for (int r = 0; r < RR; ++r) acc += wr[r] * dbc[tok * 44 + r];
    sdt[l][gg] = (acc > 20.f) ? acc : log1pf(expf(acc));
  }
  #pragma unroll
  for (int j = t; j < 512; j += 128) {
    int l = j >> 4, ss = j & 15;
    sB[l][ss] = dbc[(ib * 32 + l) * 44 + RR + ss];
    sC[l][ss] = dbc[(ib * 32 + l) * 44 + RR + SS + ss];
  }
  if (t < 8) sDsk[t] = Dskip[i * DI + di0 + t];
  float A = -expf(A_log[((size_t)i * DI + di) * SS + s]);
  float h = 0.f;
  __syncthreads();
  #pragma unroll
  for (int l = 0; l < 32; ++l) {
    float dtt = sdt[l][g];
    h = expf(dtt * A) * h + dtt * sxc[l][g] * sB[l][s];
    spp[l * 136 + g * 17 + s] = h * sC[l][s];
  }
  __syncthreads();
  #pragma unroll
  for (int p = 0; p < 2; ++p) {
    int idx = p * 128 + t;
    int l = idx >> 3, g2 = idx & 7;
    float sum = 0.f;
    #pragma unroll
    for (int s2 = 0; s2 < 16; ++s2) sum += spp[l * 136 + g2 * 17 + s2];
    float xt = sxc[l][g2];
    float z  = sz[l][g2];
    float yv = (sum + sDsk[g2] * xt) * (z / (1.f + expf(-z)));
    y[(size_t)(ib * 32 + l) * DI + di0 + g2] = yv;
    sy[l][g2] = yv;
  }
  __syncthreads();
  if (t < 8) {
    float sum = 0.f;
    #pragma unroll
    for (int l = 0; l < 32; ++l) sum += sy[l][t];
    ymean[ib * DI + di0 + t] = sum * (1.f / 32.f);
  }
}

// ---------------- K5: mz = up_b + up_w @ (out_w @ {y[tok] | ymean}) ; 198 jobs ----------------
// grid = 198, block = 384
__global__ void k_mz(const float* __restrict__ y, const float* __restrict__ ymean,
                     const float* __restrict__ out_w, const float* __restrict__ up_w,
                     const float* __restrict__ up_b, float* __restrict__ zrow) {
  int j = blockIdx.x;
  int t = threadIdx.x;
  __shared__ float src[DI];
  __shared__ float pa[384];
  __shared__ float mrowL[CC];
  int i = (j < 192) ? (j >> 6) : (j - 192) / BB;
  src[t] = (j < 192) ? y[(size_t)j * DI + t] : ymean[(j - 192) * DI + t];
  __syncthreads();
  {
    int o = t >> 1, half = t & 1;
    const float4* wr = (const float4*)(out_w + ((size_t)i * CC + o) * DI);
    const float4* sv = (const float4*)src;
    float acc = 0.f;
    #pragma unroll 8
    for (int c4 = half * 48; c4 < half * 48 + 48; ++c4) {
      float4 a = wr[c4], bq = sv[c4];
      acc += a.x * bq.x + a.y * bq.y + a.z * bq.z + a.w * bq.w;
    }
    pa[t] = acc;
  }
  __syncthreads();
  if (t < 192) mrowL[t] = pa[2 * t] + pa[2 * t + 1];
  __syncthreads();
  {
    int o = t >> 1, half = t & 1;
    const float4* ur = (const float4*)(up_w + ((size_t)i * CC + o) * CC);
    const float4* mv = (const float4*)mrowL;
    float acc = 0.f;
    #pragma unroll 8
    for (int c4 = half * 24; c4 < half * 24 + 24; ++c4) {
      float4 a = ur[c4], bq = mv[c4];
      acc += a.x * bq.x + a.y * bq.y + a.z * bq.z + a.w * bq.w;
    }
    pa[t] = acc;
  }
  __syncthreads();
  if (t < 192) zrow[(size_t)j * CC + t] = up_b[i * CC + t] + pa[2 * t] + pa[2 * t + 1];
}

// ---------------- K6: gate per token: (Ws@z || Wg@zm) -> relu -> Wm -> sigmoid -> po ----------------
// grid = 192, block = 384
__global__ void k_gate(const float* __restrict__ zrow, const float* __restrict__ Wg_w,
                       const float* __restrict__ Wg_b, const float* __restrict__ Ws_w,
                       const float* __restrict__ Ws_b, const float* __restrict__ Wm_w,
                       const float* __restrict__ Wm_b, const float* __restrict__ po_w,
                       float* __restrict__ P) {
  int blk = blockIdx.x; int gb = blk >> 5; int g = gb / BB, b = gb - g * BB;
  int o1 = (g == 0) ? 1 : 0, o2 = (g == 2) ? 1 : 2;
  int t = threadIdx.x;
  __shared__ float zr[CC], zm[2][CC], arow[CC], ygr[CC];
  __shared__ float pa[384], pb[384];
  if (t < CC) {
    zr[t] = zrow[(size_t)blk * CC + t];
    zm[0][t] = zrow[(size_t)(192 + o1 * BB + b) * CC + t];
  } else {
    int tt = t - CC;
    zm[1][tt] = zrow[(size_t)(192 + o2 * BB + b) * CC + tt];
  }
  __syncthreads();
  int o = (t < 192) ? t : t - 192;
  int ph = (t < 192) ? 0 : 1;
  {
    const float4* wr = (const float4*)(Ws_w + (size_t)o * CC);
    const float4* zv = (const float4*)zr;
    float acc = 0.f;
    #pragma unroll 4
    for (int c4 = ph * 24; c4 < ph * 24 + 24; ++c4) {
      float4 a = wr[c4], bq = zv[c4];
      acc += a.x * bq.x + a.y * bq.y + a.z * bq.z + a.w * bq.w;
    }
    pa[t] = acc;
    const float4* gwr = (const float4*)(Wg_w + (size_t)o * 2 * CC + ph * CC);
    const float4* gmv = (const float4*)zm[ph];
    float acc2 = 0.f;
    #pragma unroll 4
    for (int c4 = 0; c4 < 48; ++c4) {
      float4 a = gwr[c4], bq = gmv[c4];
      acc2 += a.x * bq.x + a.y * bq.y + a.z * bq.z + a.w * bq.w;
    }
    pb[t] = acc2;
  }
  __syncthreads();
  if (t < 192) {
    float a = (Ws_b[t] + pa[t] + pa[t + 192]) + (Wg_b[t] + pb[t] + pb[t + 192]);
    arow[t] = a > 0.f ? a : 0.f;
  }
  __syncthreads();
  {
    const float4* mr = (const float4*)(Wm_w + (size_t)o * CC);
    const float4* av = (const float4*)arow;
    float acc = 0.f;
    #pragma unroll 4
    for (int c4 = ph * 24; c4 < ph * 24 + 24; ++c4) {
      float4 a = mr[c4], bq = av[c4];
      acc += a.x * bq.x + a.y * bq.y + a.z * bq.z + a.w * bq.w;
    }
    pa[t] = acc;
  }
  __syncthreads();
  if (t < 192) {
    float am = Wm_b[t] + pa[t] + pa[t + 192];
    am = 1.f / (1.f + expf(-am));
    ygr[t] = am * zr[t];
  }
  __syncthreads();
  {
    const float4* pr = (const float4*)(po_w + (size_t)o * (3 * CC) + g * CC);
    const float4* yv = (const float4*)ygr;
    float acc = 0.f;
    #pragma unroll 4
    for (int c4 = ph * 24; c4 < ph * 24 + 24; ++c4) {
      float4 a = pr[c4], bq = yv[c4];
      acc += a.x * bq.x + a.y * bq.y + a.z * bq.z + a.w * bq.w;
    }
    pb[t] = acc;
  }
  __syncthreads();
  if (t < 192) P[(size_t)blk * CC + t] = pb[t] + pb[t + 192];
}

// ---------------- K7: final: warp-parallel separable stats + broadcast + residual ----------------
// grid = B*C*2, block = 256
__global__ void k_final(const float* __restrict__ x, const float* __restrict__ P,
                        const float* __restrict__ po_b, const float* __restrict__ rs_p,
                        float* __restrict__ out) {
  int bc = blockIdx.x >> 1; int half = blockIdx.x & 1;
  int b = bc / CC, c = bc % CC;
  __shared__ float p0[32], p1[32], p2[32];
  __shared__ float sbase;
  int t = threadIdx.x;
  if (t < 32) {
    float v0 = P[((0 * BB + b) * 32 + t) * CC + c];
    float v1 = P[((1 * BB + b) * 32 + t) * CC + c];
    float v2 = P[((2 * BB + b) * 32 + t) * CC + c];
    float s0 = v0, q0 = v0 * v0, s1 = v1, q1 = v1 * v1, s2 = v2, q2 = v2 * v2;
    #pragma unroll
    for (int off = 16; off > 0; off >>= 1) {
      s0 += __shfl_xor(s0, off, 32); q0 += __shfl_xor(q0, off, 32);
      s1 += __shfl_xor(s1, off, 32); q1 += __shfl_xor(q1, off, 32);
      s2 += __shfl_xor(s2, off, 32); q2 += __shfl_xor(q2, off, 32);
    }
    float m0 = s0 * (1.f / 32.f), m1 = s1 * (1.f / 32.f), m2 = s2 * (1.f / 32.f);
    float var = (q0 * (1.f / 32.f) - m0 * m0) + (q1 * (1.f / 32.f) - m1 * m1) + (q2 * (1.f / 32.f) - m2 * m2);
    float mu = po_b[c] + m0 + m1 + m2;
    float sc = rs_p[0] * rsqrtf(var + 1e-5f);
    p0[t] = v0 * sc; p1[t] = v1 * sc; p2[t] = v2 * sc;
    if (t == 0) sbase = sc * (po_b[c] - mu);
  }
  __syncthreads();
  float basev = sbase;
  const float4* xin = (const float4*)(x + (size_t)bc * 32768);
  float4* xo = (float4*)(out + (size_t)bc * 32768);
  int q0i = half * 4096;
  #pragma unroll 4
  for (int q = q0i + t; q < q0i + 4096; q += 256) {
    int d = q >> 8, h = (q >> 3) & 31, w4 = (q & 7) * 4;
    float add = basev + p0[d] + p1[h];
    float4 v = xin[q];
    v.x += add + p2[w4];
    v.y += add + p2[w4 + 1];
    v.z += add + p2[w4 + 2];
    v.w += add + p2[w4 + 3];
    xo[q] = v;
  }
}

extern "C" void kernel_launch(void* const* d_in, const int* in_sizes, int n_in,
                              void* d_out, int out_size, void* d_ws, size_t ws_size,
                              hipStream_t stream) {
  const float* x      = (const float*)d_in[0];
  const float* ln_w   = (const float*)d_in[1];
  const float* ln_b   = (const float*)d_in[2];
  const float* in_w   = (const float*)d_in[3];
  const float* conv_w = (const float*)d_in[4];
  const float* conv_b = (const float*)d_in[5];
  const float* xp_w   = (const float*)d_in[6];
  const float* dt_w   = (const float*)d_in[7];
  const float* dt_b   = (const float*)d_in[8];
  const float* A_log  = (const float*)d_in[9];
  const float* Dskip  = (const float*)d_in[10];
  const float* out_w  = (const float*)d_in[11];
  const float* up_w   = (const float*)d_in[12];
  const float* up_b   = (const float*)d_in[13];
  const float* Wg_w   = (const float*)d_in[14];
  const float* Wg_b   = (const float*)d_in[15];
  const float* Ws_w   = (const float*)d_in[16];
  const float* Ws_b   = (const float*)d_in[17];
  const float* Wm_w   = (const float*)d_in[18];
  const float* Wm_b   = (const float*)d_in[19];
  const float* po_w   = (const float*)d_in[20];
  const float* po_b   = (const float*)d_in[21];
  const float* rs_p   = (const float*)d_in[22];
  float* out = (float*)d_out;

  float* ws    = (float*)d_ws;
  float* seq   = ws;                 // 36864
  float* xmz   = seq   + 36864;      // 147456
  float* xc    = xmz   + 147456;     // 73728
  float* dbc   = xc    + 73728;      // 8448
  float* y     = dbc   + 8448;       // 73728
  float* ymean = y     + 73728;      // 2304
  float* zrow  = ymean + 2304;       // 38016
  float* P     = zrow  + 38016;      // 36864

  k_reduce  <<<dim3(BB * CC),     dim3(1024), 0, stream>>>(x, seq);
  k_lninproj<<<dim3(576),         dim3(256),  0, stream>>>(seq, ln_w, ln_b, in_w, xmz);
  k_convxp  <<<dim3(192),         dim3(384),  0, stream>>>(xmz, conv_w, conv_b, xp_w, xc, dbc);
  k_scan    <<<dim3(288),         dim3(128),  0, stream>>>(dbc, xc, xmz, dt_w, dt_b, A_log,
                                                           Dskip, y, ymean);
  k_mz      <<<dim3(198),         dim3(384),  0, stream>>>(y, ymean, out_w, up_w, up_b, zrow);
  k_gate    <<<dim3(192),         dim3(384),  0, stream>>>(zrow, Wg_w, Wg_b, Ws_w, Ws_b,
                                                           Wm_w, Wm_b, po_w, P);
  k_final   <<<dim3(BB * CC * 2), dim3(256),  0, stream>>>(x, P, po_b, rs_p, out);
}

// Round 9
// 99.290 us; speedup vs baseline: 2.3952x; 1.1310x over previous
//
#include <hip/hip_runtime.h>
#include <math.h>

#define BB 2
#define CC 192
#define DI 384
#define SS 16
#define RR 12
#define KK 4

// ---------------- K1: one pass over x, float4; fixed-h/w-slot scheme ----------------
// grid = B*C, block = 256. thread t: h = t>>3, w4-slot = t&7; iteration k = d.
__global__ void k_reduce(const float* __restrict__ x, float* __restrict__ seq) {
  int bc = blockIdx.x; int b = bc / CC, c = bc % CC;
  const float4* xin = (const float4*)(x + (size_t)bc * 32768);
  int t = threadIdx.x;
  int wid = t >> 6;
  __shared__ float pd[32][4];
  __shared__ float swa[256 * 4];
  float hacc = 0.f;
  float4 wacc = {0.f, 0.f, 0.f, 0.f};
  #pragma unroll 4
  for (int k = 0; k < 32; ++k) {
    float4 v = xin[k * 256 + t];
    float s = v.x + v.y + v.z + v.w;
    hacc += s;
    wacc.x += v.x; wacc.y += v.y; wacc.z += v.z; wacc.w += v.w;
    float ss = s;
    #pragma unroll
    for (int off = 32; off > 0; off >>= 1) ss += __shfl_down(ss, off, 64);
    if ((t & 63) == 0) pd[k][wid] = ss;
  }
  // per-h: 8 lanes share h = t>>3
  #pragma unroll
  for (int off = 4; off > 0; off >>= 1) hacc += __shfl_down(hacc, off, 8);
  if ((t & 7) == 0)
    seq[((1 * BB + b) * 32 + (t >> 3)) * CC + c] = hacc * (1.f / 1024.f);
  ((float4*)swa)[t] = wacc;
  __syncthreads();
  if (t < 32) {
    float s0 = pd[t][0] + pd[t][1] + pd[t][2] + pd[t][3];
    seq[((0 * BB + b) * 32 + t) * CC + c] = s0 * (1.f / 1024.f);
    // w = t: slot j = t>>2, component t&3 -> flat addr t + 32m (bank-clean)
    float s2 = 0.f;
    #pragma unroll
    for (int m = 0; m < 32; ++m) s2 += swa[t + 32 * m];
    seq[((2 * BB + b) * 32 + t) * CC + c] = s2 * (1.f / 1024.f);
  }
}

// ---------------- K2: LN + in-proj, 2-way split dots ----------------
// grid = 768 (192 tok x 4 chunks of 192 outs), block = 384
__global__ void k_lninproj(const float* __restrict__ seq, const float* __restrict__ ln_w,
                           const float* __restrict__ ln_b, const float* __restrict__ in_w,
                           float* __restrict__ xmz) {
  int blk = blockIdx.x;
  int tok = blk >> 2, chunk = blk & 3;
  int i = tok >> 6;
  int t = threadIdx.x;
  __shared__ float srow[CC];
  __shared__ float sw[6], qw[6];
  __shared__ float pa[384];
  float v = (t < CC) ? seq[tok * CC + t] : 0.f;
  float s = v, q = v * v;
  #pragma unroll
  for (int off = 32; off > 0; off >>= 1) { s += __shfl_down(s, off, 64); q += __shfl_down(q, off, 64); }
  if ((t & 63) == 0) { sw[t >> 6] = s; qw[t >> 6] = q; }
  __syncthreads();
  float S = sw[0] + sw[1] + sw[2];
  float Q = qw[0] + qw[1] + qw[2];
  float mu = S / CC;
  float var = Q / CC - mu * mu;
  if (t < CC) srow[t] = (v - mu) * rsqrtf(var + 1e-5f) * ln_w[i * CC + t] + ln_b[i * CC + t];
  __syncthreads();
  int o = t >> 1, half = t & 1;
  int j = chunk * 192 + o;
  const float4* wr = (const float4*)(in_w + ((size_t)i * 768 + j) * CC);
  const float4* sr = (const float4*)srow;
  float acc = 0.f;
  #pragma unroll 8
  for (int c4 = half * 24; c4 < half * 24 + 24; ++c4) {
    float4 a = wr[c4], bq = sr[c4];
    acc += a.x * bq.x + a.y * bq.y + a.z * bq.z + a.w * bq.w;
  }
  pa[t] = acc;
  __syncthreads();
  if ((t & 1) == 0) xmz[(size_t)tok * 768 + j] = pa[t] + pa[t + 1];
}

// ---------------- K3: conv+silu + xp-proj, per token ----------------
// grid = 192, block = 384
__global__ void k_convxp(const float* __restrict__ xmz, const float* __restrict__ conv_w,
                         const float* __restrict__ conv_b, const float* __restrict__ xp_w,
                         float* __restrict__ xc, float* __restrict__ dbc) {
  int tok = blockIdx.x; int l = tok & 31; int tb = tok >> 5; int i = tb / BB;
  int t = threadIdx.x;
  __shared__ float xcl[DI];
  {
    int di = t;
    const float* cw = conv_w + ((size_t)i * DI + di) * KK;
    float acc = conv_b[i * DI + di];
    #pragma unroll
    for (int k = 0; k < KK; ++k) {
      int ls = l + k - 3;
      if (ls >= 0) acc += cw[k] * xmz[(size_t)(tb * 32 + ls) * 768 + di];
    }
    acc = acc / (1.f + expf(-acc));
    xcl[di] = acc;
    xc[(size_t)tok * DI + di] = acc;
  }
  __syncthreads();
  if (t < 352) {
    int o = t >> 3, ln8 = t & 7;
    const float4* wr = (const float4*)(xp_w + ((size_t)i * 44 + o) * DI);
    const float4* xv = (const float4*)xcl;
    float acc = 0.f;
    #pragma unroll
    for (int c4 = ln8 * 12; c4 < ln8 * 12 + 12; ++c4) {
      float4 a = wr[c4], bq = xv[c4];
      acc += a.x * bq.x + a.y * bq.y + a.z * bq.z + a.w * bq.w;
    }
    #pragma unroll
    for (int off = 4; off > 0; off >>= 1) acc += __shfl_xor(acc, off, 8);
    if (ln8 == 0) dbc[tok * 44 + o] = acc;
  }
}

// ---------------- K4: scan (dt-proj+softplus inlined at staging) ----------------
// grid = 288 (6 ib x 48 chunks), block = 128 (8 di x 16 s)
__global__ void k_scan(const float* __restrict__ dbc, const float* __restrict__ xc,
                       const float* __restrict__ xmz, const float* __restrict__ dt_w,
                       const float* __restrict__ dt_b, const float* __restrict__ A_log,
                       const float* __restrict__ Dskip, float* __restrict__ y,
                       float* __restrict__ ymean) {
  int ib = blockIdx.x / 48;
  int di0 = (blockIdx.x % 48) * 8;
  int i = ib / BB;
  int t = threadIdx.x;
  int g = t >> 4, s = t & 15;
  int di = di0 + g;
  __shared__ float sdt[32][8], sxc[32][8], sz[32][8];
  __shared__ float sB[32][SS], sC[32][SS];
  __shared__ float spp[32 * 136];
  __shared__ float sy[32][8];
  __shared__ float sDsk[8];
  #pragma unroll
  for (int j = t; j < 256; j += 128) {
    int l = j >> 3, gg = j & 7;
    int tok = ib * 32 + l;
    sxc[l][gg] = xc[(size_t)tok * DI + di0 + gg];
    sz[l][gg]  = xmz[(size_t)tok * 768 + DI + di0 + gg];
    const float* wr = dt_w + ((size_t)i * DI + di0 + gg) * RR;
    float acc = dt_b[i * DI + di0 + gg];
    #pragma unroll
    for (int r = 0; r < RR; ++r) acc += wr[r] * dbc[tok * 44 + r];
    sdt[l][gg] = (acc > 20.f) ? acc : log1pf(expf(acc));
  }
  #pragma unroll
  for (int j = t; j < 512; j += 128) {
    int l = j >> 4, ss = j & 15;
    sB[l][ss] = dbc[(ib * 32 + l) * 44 + RR + ss];
    sC[l][ss] = dbc[(ib * 32 + l) * 44 + RR + SS + ss];
  }
  if (t < 8) sDsk[t] = Dskip[i * DI + di0 + t];
  float A = -expf(A_log[((size_t)i * DI + di) * SS + s]);
  float h = 0.f;
  __syncthreads();
  #pragma unroll
  for (int l = 0; l < 32; ++l) {
    float dtt = sdt[l][g];
    h = expf(dtt * A) * h + dtt * sxc[l][g] * sB[l][s];
    spp[l * 136 + g * 17 + s] = h * sC[l][s];
  }
  __syncthreads();
  #pragma unroll
  for (int p = 0; p < 2; ++p) {
    int idx = p * 128 + t;
    int l = idx >> 3, g2 = idx & 7;
    float sum = 0.f;
    #pragma unroll
    for (int s2 = 0; s2 < 16; ++s2) sum += spp[l * 136 + g2 * 17 + s2];
    float xt = sxc[l][g2];
    float z  = sz[l][g2];
    float yv = (sum + sDsk[g2] * xt) * (z / (1.f + expf(-z)));
    y[(size_t)(ib * 32 + l) * DI + di0 + g2] = yv;
    sy[l][g2] = yv;
  }
  __syncthreads();
  if (t < 8) {
    float sum = 0.f;
    #pragma unroll
    for (int l = 0; l < 32; ++l) sum += sy[l][t];
    ymean[ib * DI + di0 + t] = sum * (1.f / 32.f);
  }
}

// ---------------- K5: mz = up_b + up_w @ (out_w @ {y[tok] | ymean}) ; 4-way split ----------------
// grid = 198, block = 768
__global__ void k_mz(const float* __restrict__ y, const float* __restrict__ ymean,
                     const float* __restrict__ out_w, const float* __restrict__ up_w,
                     const float* __restrict__ up_b, float* __restrict__ zrow) {
  int j = blockIdx.x;
  int t = threadIdx.x;
  __shared__ float src[DI];
  __shared__ float pa[768];
  __shared__ float mrowL[CC];
  int i = (j < 192) ? (j >> 6) : (j - 192) / BB;
  if (t < DI) src[t] = (j < 192) ? y[(size_t)j * DI + t] : ymean[(j - 192) * DI + t];
  __syncthreads();
  int o = t >> 2, qr = t & 3;
  {
    const float4* wr = (const float4*)(out_w + ((size_t)i * CC + o) * DI);
    const float4* sv = (const float4*)src;
    float acc = 0.f;
    #pragma unroll 8
    for (int c4 = qr * 24; c4 < qr * 24 + 24; ++c4) {
      float4 a = wr[c4], bq = sv[c4];
      acc += a.x * bq.x + a.y * bq.y + a.z * bq.z + a.w * bq.w;
    }
    pa[t] = acc;
  }
  __syncthreads();
  if (t < 192) {
    float4 pv = ((const float4*)pa)[t];
    mrowL[t] = pv.x + pv.y + pv.z + pv.w;
  }
  __syncthreads();
  {
    const float4* ur = (const float4*)(up_w + ((size_t)i * CC + o) * CC);
    const float4* mv = (const float4*)mrowL;
    float acc = 0.f;
    #pragma unroll 8
    for (int c4 = qr * 12; c4 < qr * 12 + 12; ++c4) {
      float4 a = ur[c4], bq = mv[c4];
      acc += a.x * bq.x + a.y * bq.y + a.z * bq.z + a.w * bq.w;
    }
    pa[t] = acc;
  }
  __syncthreads();
  if (t < 192) {
    float4 pv = ((const float4*)pa)[t];
    zrow[(size_t)j * CC + t] = up_b[i * CC + t] + pv.x + pv.y + pv.z + pv.w;
  }
}

// ---------------- K6: gate per token, 4-way split dots ----------------
// grid = 192, block = 768
__global__ void k_gate(const float* __restrict__ zrow, const float* __restrict__ Wg_w,
                       const float* __restrict__ Wg_b, const float* __restrict__ Ws_w,
                       const float* __restrict__ Ws_b, const float* __restrict__ Wm_w,
                       const float* __restrict__ Wm_b, const float* __restrict__ po_w,
                       float* __restrict__ P) {
  int blk = blockIdx.x; int gb = blk >> 5; int g = gb / BB, b = gb - g * BB;
  int o1 = (g == 0) ? 1 : 0, o2 = (g == 2) ? 1 : 2;
  int t = threadIdx.x;
  __shared__ float zr[CC], zm0[CC], zm1[CC], arow[CC], ygr[CC];
  __shared__ float pa[768], pb[768];
  if (t < CC)            zr[t]        = zrow[(size_t)blk * CC + t];
  else if (t < 2 * CC)   zm0[t - CC]  = zrow[(size_t)(192 + o1 * BB + b) * CC + (t - CC)];
  else if (t < 3 * CC)   zm1[t - 2*CC]= zrow[(size_t)(192 + o2 * BB + b) * CC + (t - 2*CC)];
  __syncthreads();
  int o = t >> 2, qr = t & 3;
  { // Ws (12 f4) and Wg (24 f4: qr<2 -> zm0 half, qr>=2 -> zm1 half)
    const float4* wr = (const float4*)(Ws_w + (size_t)o * CC);
    const float4* zv = (const float4*)zr;
    float acc = 0.f;
    #pragma unroll 4
    for (int c4 = qr * 12; c4 < qr * 12 + 12; ++c4) {
      float4 a = wr[c4], bq = zv[c4];
      acc += a.x * bq.x + a.y * bq.y + a.z * bq.z + a.w * bq.w;
    }
    pa[t] = acc;
    const float4* gwr = (const float4*)(Wg_w + (size_t)o * 2 * CC);
    float acc2 = 0.f;
    #pragma unroll 4
    for (int c4 = qr * 24; c4 < qr * 24 + 24; ++c4) {
      float4 a = gwr[c4];
      float4 bq = (c4 < 48) ? ((const float4*)zm0)[c4] : ((const float4*)zm1)[c4 - 48];
      acc2 += a.x * bq.x + a.y * bq.y + a.z * bq.z + a.w * bq.w;
    }
    pb[t] = acc2;
  }
  __syncthreads();
  if (t < 192) {
    float4 sa = ((const float4*)pa)[t];
    float4 sb = ((const float4*)pb)[t];
    float a = (Ws_b[t] + sa.x + sa.y + sa.z + sa.w) + (Wg_b[t] + sb.x + sb.y + sb.z + sb.w);
    arow[t] = a > 0.f ? a : 0.f;
  }
  __syncthreads();
  {
    const float4* mr = (const float4*)(Wm_w + (size_t)o * CC);
    const float4* av = (const float4*)arow;
    float acc = 0.f;
    #pragma unroll 4
    for (int c4 = qr * 12; c4 < qr * 12 + 12; ++c4) {
      float4 a = mr[c4], bq = av[c4];
      acc += a.x * bq.x + a.y * bq.y + a.z * bq.z + a.w * bq.w;
    }
    pa[t] = acc;
  }
  __syncthreads();
  if (t < 192) {
    float4 sa = ((const float4*)pa)[t];
    float am = Wm_b[t] + sa.x + sa.y + sa.z + sa.w;
    am = 1.f / (1.f + expf(-am));
    ygr[t] = am * zr[t];
  }
  __syncthreads();
  {
    const float4* pr = (const float4*)(po_w + (size_t)o * (3 * CC) + g * CC);
    const float4* yv = (const float4*)ygr;
    float acc = 0.f;
    #pragma unroll 4
    for (int c4 = qr * 12; c4 < qr * 12 + 12; ++c4) {
      float4 a = pr[c4], bq = yv[c4];
      acc += a.x * bq.x + a.y * bq.y + a.z * bq.z + a.w * bq.w;
    }
    pb[t] = acc;
  }
  __syncthreads();
  if (t < 192) {
    float4 sb = ((const float4*)pb)[t];
    P[(size_t)blk * CC + t] = sb.x + sb.y + sb.z + sb.w;
  }
}

// ---------------- K7: final: warp-parallel separable stats + broadcast + residual ----------------
// grid = B*C*2, block = 256
__global__ void k_final(const float* __restrict__ x, const float* __restrict__ P,
                        const float* __restrict__ po_b, const float* __restrict__ rs_p,
                        float* __restrict__ out) {
  int bc = blockIdx.x >> 1; int half = blockIdx.x & 1;
  int b = bc / CC, c = bc % CC;
  __shared__ float p0[32], p1[32], p2[32];
  __shared__ float sbase;
  int t = threadIdx.x;
  if (t < 32) {
    float v0 = P[((0 * BB + b) * 32 + t) * CC + c];
    float v1 = P[((1 * BB + b) * 32 + t) * CC + c];
    float v2 = P[((2 * BB + b) * 32 + t) * CC + c];
    float s0 = v0, q0 = v0 * v0, s1 = v1, q1 = v1 * v1, s2 = v2, q2 = v2 * v2;
    #pragma unroll
    for (int off = 16; off > 0; off >>= 1) {
      s0 += __shfl_xor(s0, off, 32); q0 += __shfl_xor(q0, off, 32);
      s1 += __shfl_xor(s1, off, 32); q1 += __shfl_xor(q1, off, 32);
      s2 += __shfl_xor(s2, off, 32); q2 += __shfl_xor(q2, off, 32);
    }
    float m0 = s0 * (1.f / 32.f), m1 = s1 * (1.f / 32.f), m2 = s2 * (1.f / 32.f);
    float var = (q0 * (1.f / 32.f) - m0 * m0) + (q1 * (1.f / 32.f) - m1 * m1) + (q2 * (1.f / 32.f) - m2 * m2);
    float mu = po_b[c] + m0 + m1 + m2;
    float sc = rs_p[0] * rsqrtf(var + 1e-5f);
    p0[t] = v0 * sc; p1[t] = v1 * sc; p2[t] = v2 * sc;
    if (t == 0) sbase = sc * (po_b[c] - mu);
  }
  __syncthreads();
  float basev = sbase;
  const float4* xin = (const float4*)(x + (size_t)bc * 32768);
  float4* xo = (float4*)(out + (size_t)bc * 32768);
  int q0i = half * 4096;
  #pragma unroll 4
  for (int q = q0i + t; q < q0i + 4096; q += 256) {
    int d = q >> 8, h = (q >> 3) & 31, w4 = (q & 7) * 4;
    float add = basev + p0[d] + p1[h];
    float4 v = xin[q];
    v.x += add + p2[w4];
    v.y += add + p2[w4 + 1];
    v.z += add + p2[w4 + 2];
    v.w += add + p2[w4 + 3];
    xo[q] = v;
  }
}

extern "C" void kernel_launch(void* const* d_in, const int* in_sizes, int n_in,
                              void* d_out, int out_size, void* d_ws, size_t ws_size,
                              hipStream_t stream) {
  const float* x      = (const float*)d_in[0];
  const float* ln_w   = (const float*)d_in[1];
  const float* ln_b   = (const float*)d_in[2];
  const float* in_w   = (const float*)d_in[3];
  const float* conv_w = (const float*)d_in[4];
  const float* conv_b = (const float*)d_in[5];
  const float* xp_w   = (const float*)d_in[6];
  const float* dt_w   = (const float*)d_in[7];
  const float* dt_b   = (const float*)d_in[8];
  const float* A_log  = (const float*)d_in[9];
  const float* Dskip  = (const float*)d_in[10];
  const float* out_w  = (const float*)d_in[11];
  const float* up_w   = (const float*)d_in[12];
  const float* up_b   = (const float*)d_in[13];
  const float* Wg_w   = (const float*)d_in[14];
  const float* Wg_b   = (const float*)d_in[15];
  const float* Ws_w   = (const float*)d_in[16];
  const float* Ws_b   = (const float*)d_in[17];
  const float* Wm_w   = (const float*)d_in[18];
  const float* Wm_b   = (const float*)d_in[19];
  const float* po_w   = (const float*)d_in[20];
  const float* po_b   = (const float*)d_in[21];
  const float* rs_p   = (const float*)d_in[22];
  float* out = (float*)d_out;

  float* ws    = (float*)d_ws;
  float* seq   = ws;                 // 36864
  float* xmz   = seq   + 36864;      // 147456
  float* xc    = xmz   + 147456;     // 73728
  float* dbc   = xc    + 73728;      // 8448
  float* y     = dbc   + 8448;       // 73728
  float* ymean = y     + 73728;      // 2304
  float* zrow  = ymean + 2304;       // 38016
  float* P     = zrow  + 38016;      // 36864

  k_reduce  <<<dim3(BB * CC),     dim3(256), 0, stream>>>(x, seq);
  k_lninproj<<<dim3(768),         dim3(384), 0, stream>>>(seq, ln_w, ln_b, in_w, xmz);
  k_convxp  <<<dim3(192),         dim3(384), 0, stream>>>(xmz, conv_w, conv_b, xp_w, xc, dbc);
  k_scan    <<<dim3(288),         dim3(128), 0, stream>>>(dbc, xc, xmz, dt_w, dt_b, A_log,
                                                          Dskip, y, ymean);
  k_mz      <<<dim3(198),         dim3(768), 0, stream>>>(y, ymean, out_w, up_w, up_b, zrow);
  k_gate    <<<dim3(192),         dim3(768), 0, stream>>>(zrow, Wg_w, Wg_b, Ws_w, Ws_b,
                                                          Wm_w, Wm_b, po_w, P);
  k_final   <<<dim3(BB * CC * 2), dim3(256), 0, stream>>>(x, P, po_b, rs_p, out);
}